// Round 6
// baseline (51.624 us; speedup 1.0000x reference)
//
#include <hip/hip_runtime.h>
#include <math.h>

// PolyaTree R6: rank-based lookup instead of 7-level descent.
// Per dim: the 127 internal-node split values, sorted, are the leaf
// boundaries. leaf(x) = rank(x) = #(boundaries < x)  (descent "x<=split ->
// left" makes leaves (lo,hi], so strict-less rank is exact, incl. ties).
// A 1024-cell uniform grid (cell = (int)(x*1024.0f), exact pow2 multiply,
// monotone & identical in build/eval) stores (base_rank<<8 | k) per cell;
// rank = base + compares against the <=k in-cell sorted boundaries.
// Compares past the cell are auto-false (later boundaries > x), so one
// unconditional compare covers k<=1; k>=2 takes a short divergent loop.
// Eval: 3 LDS reads/point-dim (was 8). Values via the proven bit-exact
// descent (R3, absmax 0.03).

constexpr int DIMS  = 16;
constexpr int NODES = 255;   // 2^8 - 1
constexpr int GRIDC = 1024;  // cells per dim

// workspace layout, u32 units:
constexpr int BND_OFF  = 0;                  // 16*128 f32  (sorted bounds, pad +INF)
constexpr int VAL_OFF  = 2048;               // 16*128 f32  (value per rank)
constexpr int CELL_OFF = 4096;               // 16*1024 u16 (base<<8 | k)
constexpr int WS_U32   = 12288;              // 48 KB total

// --- exact-mirror node interval descent (validated R3/R5) ---
__device__ void node_lohi(const float* s, int j, float& lo, float& hi, float& acc) {
#pragma clang fp contract(off)
    unsigned key = (unsigned)(j + 1);   // 1 then path bits (0 = left)
    int level = 31 - __clz(key);
    lo = 0.0f; hi = 1.0f; acc = 0.0f;
    int i = 0;
    for (int tb = level - 1; tb >= 0; --tb) {
        float b = s[i];
        acc += logf(b);
        float len = hi - lo;
        float split = lo + b * len;     // EXACT mirror of reference (no fma)
        unsigned bit = (key >> tb) & 1u;
        if (bit == 0u) { hi = split; }
        else { lo = split; hi = split + (1.0f - b) * len; }
        i = 2 * i + 1 + (int)bit;
    }
}

__device__ float node_split(const float* s, int j) {
#pragma clang fp contract(off)
    float lo, hi, acc;
    node_lohi(s, j, lo, hi, acc);
    return lo + s[j] * (hi - lo);
}

// one block per dim
__global__ __launch_bounds__(256) void build_tables(
    const float* __restrict__ samples,   // (16,255)
    unsigned* __restrict__ ws)
{
    const int d   = blockIdx.x;
    const int tid = threadIdx.x;
    const float* s = samples + d * NODES;

    float* bnd_g = (float*)(ws + BND_OFF) + d * 128;
    float* val_g = (float*)(ws + VAL_OFF) + d * 128;
    unsigned short* cell_g = (unsigned short*)(ws + CELL_OFF) + d * GRIDC;

    __shared__ float raw[127];
    __shared__ float srt[128];

    if (tid < 127) raw[tid] = node_split(s, tid);   // internal-node splits
    if (tid == 127) srt[127] = INFINITY;            // pad (auto-false slot)
    __syncthreads();

    if (tid < 127) {                                // rank-sort, total order
        float v = raw[tid];
        int rank = 0;
        for (int j = 0; j < 127; ++j) {
            float w = raw[j];
            rank += (int)((w < v) || (w == v && j < tid));
        }
        srt[rank] = v;
    }
    __syncthreads();

    if (tid < 128) bnd_g[tid] = srt[tid];

    // cell table: base = #(cellof(b) < c), k = #(cellof(b) == c)
    for (int c = tid; c < GRIDC; c += 256) {
        int base = 0, k = 0;
        for (int j = 0; j < 127; ++j) {
            int cb = (int)(srt[j] * 1024.0f);       // same expr as eval
            base += (int)(cb < c);
            k    += (int)(cb == c);
        }
        cell_g[c] = (unsigned short)((base << 8) | k);
    }

    // leaf values: rank of leaf = #(boundary values <= lo); skip empty leaves
    if (tid < 128) {
        int j = 127 + tid;
        float lo, hi, acc;
        node_lohi(s, j, lo, hi, acc);
        if (hi > lo) {
            float v = acc + logf(s[j]) - logf(hi - lo);
            int rank = 0;
            for (int i = 0; i < 127; ++i) rank += (int)(srt[i] <= lo);
            val_g[rank] = v;
        }
    }
}

__global__ __launch_bounds__(256) void polya_eval(
    const float* __restrict__ x,     // (n,16)
    const unsigned* __restrict__ ws, // 48 KB tables
    float* __restrict__ out,
    int n)
{
    __shared__ unsigned s_mem[WS_U32];              // 48 KB -> 3 blocks/CU
    {
        const uint4* src = (const uint4*)ws;
        uint4* dst = (uint4*)s_mem;
        for (int i = threadIdx.x; i < WS_U32 / 4; i += 256) dst[i] = src[i];
    }
    __syncthreads();
    const float* s_bnd = (const float*)(s_mem + BND_OFF);
    const float* s_val = (const float*)(s_mem + VAL_OFF);
    const unsigned short* s_cell = (const unsigned short*)(s_mem + CELL_OFF);

    const int stride = gridDim.x * 256;
    for (int p = blockIdx.x * 256 + threadIdx.x; p < n; p += stride) {
        const float4* xr = reinterpret_cast<const float4*>(x + (size_t)p * DIMS);
        float4 a = xr[0], b4 = xr[1], c4 = xr[2], e4 = xr[3];
        float xs[DIMS] = {a.x, a.y, a.z, a.w,  b4.x, b4.y, b4.z, b4.w,
                          c4.x, c4.y, c4.z, c4.w,  e4.x, e4.y, e4.z, e4.w};
        float acc = 0.0f;
#pragma unroll
        for (int d = 0; d < DIMS; ++d) {
            const float xv = xs[d];
            const int c = (int)(xv * 1024.0f);      // exact pow2 scale
            const unsigned u = s_cell[(d << 10) + c];
            const int base = (int)(u >> 8);
            const int k = (int)(u & 255u);
            const float* bd = s_bnd + (d << 7);
            int r = base + (int)(xv > bd[base]);    // covers k<=1 (auto-false)
            for (int j = 1; j < k; ++j)             // rare: k>=2 cells
                r += (int)(xv > bd[base + j]);
            acc += s_val[(d << 7) + r];
        }
        out[p] = acc * 0.0625f;
    }
}

extern "C" void kernel_launch(void* const* d_in, const int* in_sizes, int n_in,
                              void* d_out, int out_size, void* d_ws, size_t ws_size,
                              hipStream_t stream) {
    const float* x       = (const float*)d_in[0];   // (n,16) f32
    const float* samples = (const float*)d_in[1];   // (16,255) f32
    float* out = (float*)d_out;
    const int n = in_sizes[0] / DIMS;
    unsigned* ws = (unsigned*)d_ws;

    build_tables<<<DIMS, 256, 0, stream>>>(samples, ws);

    // 1536 blocks = 2 rounds of 3 blocks/CU (48 KB LDS each) on 256 CUs
    polya_eval<<<1536, 256, 0, stream>>>(x, ws, out, n);
}

// Round 7
// 50.882 us; speedup vs baseline: 1.0146x; 1.0146x over previous
//
#include <hip/hip_runtime.h>
#include <math.h>

// PolyaTree R7: R3 descent (proven bit-exact) with levels 0-2 resolved from
// REGISTERS (7 wave-uniform splits/dim, loaded once, cndmask tree) and only
// levels 3-6 + leaf value from LDS: 5 narrow b32 gathers/point-dim (was 8).
// DS-pipe floor drops 19 -> ~12 us.

constexpr int DIMS  = 16;
constexpr int NODES = 255;

// ws layout (floats)
constexpr int TOP_OFF = 0;      // 16*8  : splits of nodes 0..6 (lvl0-2), [7] pad
constexpr int L3_OFF  = 128;    // 16*8  : nodes 7..14
constexpr int L4_OFF  = 256;    // 16*16 : nodes 15..30
constexpr int L5_OFF  = 512;    // 16*32 : nodes 31..62
constexpr int L6_OFF  = 1024;   // 16*64 : nodes 63..126
constexpr int VAL_OFF = 2048;   // 16*128: leaves 127..254
constexpr int WS_F    = 4096;   // 16 KB
constexpr int LDS_F   = WS_F - L3_OFF;   // 3968 floats = 15.5 KB staged

// --- exact-mirror node interval descent (validated R3/R5/R6, absmax 0.03) ---
__device__ void node_lohi(const float* s, int j, float& lo, float& hi, float& acc) {
#pragma clang fp contract(off)
    unsigned key = (unsigned)(j + 1);   // 1 then path bits (0 = left)
    int level = 31 - __clz(key);
    lo = 0.0f; hi = 1.0f; acc = 0.0f;
    int i = 0;
    for (int tb = level - 1; tb >= 0; --tb) {
        float b = s[i];
        acc += logf(b);
        float len = hi - lo;
        float split = lo + b * len;     // EXACT mirror of reference (no fma)
        unsigned bit = (key >> tb) & 1u;
        if (bit == 0u) { hi = split; }
        else { lo = split; hi = split + (1.0f - b) * len; }
        i = 2 * i + 1 + (int)bit;
    }
}

__global__ void build_luts(const float* __restrict__ samples, // (16,255)
                           float* __restrict__ ws)            // WS_F floats
{
#pragma clang fp contract(off)
    int t = blockIdx.x * blockDim.x + threadIdx.x;
    if (t >= DIMS * NODES) return;
    int d = t / NODES;
    int j = t - d * NODES;
    const float* s = samples + d * NODES;

    float lo, hi, acc;
    node_lohi(s, j, lo, hi, acc);
    float b = s[j];
    if (j < 127) {
        float split = lo + b * (hi - lo);            // exact mirror
        if (j < 7)        ws[TOP_OFF + d * 8   + j]        = split;
        else if (j < 15)  ws[L3_OFF  + d * 8   + (j - 7)]  = split;
        else if (j < 31)  ws[L4_OFF  + d * 16  + (j - 15)] = split;
        else if (j < 63)  ws[L5_OFF  + d * 32  + (j - 31)] = split;
        else              ws[L6_OFF  + d * 64  + (j - 63)] = split;
    } else {
        float v = acc + logf(b) - logf(hi - lo);     // leaf value
        ws[VAL_OFF + d * 128 + (j - 127)] = v;
    }
}

__global__ __launch_bounds__(256, 4) void polya_eval(
    const float* __restrict__ x,     // (n,16)
    const float* __restrict__ tbl,   // ws (WS_F floats)
    float* __restrict__ out,
    int n)
{
    __shared__ float s_t[LDS_F];     // lvl3..6 + values, 15.5 KB
    for (int i = threadIdx.x; i < LDS_F; i += 256) s_t[i] = tbl[L3_OFF + i];
    __syncthreads();

    // levels 0-2 splits: wave-uniform, loaded ONCE (outside the point loop)
    float S0[DIMS], S1[DIMS], S2[DIMS];              // lvl0, lvl1 (nodes 1,2)
    float C0[DIMS], C1[DIMS], C2[DIMS], C3[DIMS];    // lvl2 (nodes 3..6)
#pragma unroll
    for (int d = 0; d < DIMS; ++d) {
        const float* t = tbl + TOP_OFF + d * 8;
        S0[d] = t[0]; S1[d] = t[1]; S2[d] = t[2];
        C0[d] = t[3]; C1[d] = t[4]; C2[d] = t[5]; C3[d] = t[6];
    }

    const int stride = gridDim.x * 256;
    for (int p = blockIdx.x * 256 + threadIdx.x; p < n; p += stride) {
        const float4* xr = reinterpret_cast<const float4*>(x + (size_t)p * DIMS);
        float4 a = xr[0], b4 = xr[1], c4 = xr[2], e4 = xr[3];
        float xs[DIMS] = {a.x, a.y, a.z, a.w,  b4.x, b4.y, b4.z, b4.w,
                          c4.x, c4.y, c4.z, c4.w,  e4.x, e4.y, e4.z, e4.w};
        float acc = 0.0f;
#pragma unroll
        for (int d = 0; d < DIMS; ++d) {
            const float xv = xs[d];
            // levels 0-2: pure VALU (cmp + cndmask), no LDS
            const int b0 = (int)(xv > S0[d]);
            const float m1 = b0 ? S2[d] : S1[d];
            const int b1 = (int)(xv > m1);
            const float ta = b1 ? C1[d] : C0[d];
            const float tb = b1 ? C3[d] : C2[d];
            const float m2 = b0 ? tb : ta;
            const int b2 = (int)(xv > m2);
            int q = (b0 << 2) | (b1 << 1) | b2;               // 3 bits
            // levels 3-6 + value: 5 narrow LDS gathers
            q = (q << 1) | (int)(xv > s_t[        d * 8   + q]);  // lvl3
            q = (q << 1) | (int)(xv > s_t[128  +  d * 16  + q]);  // lvl4
            q = (q << 1) | (int)(xv > s_t[384  +  d * 32  + q]);  // lvl5
            q = (q << 1) | (int)(xv > s_t[896  +  d * 64  + q]);  // lvl6
            acc += s_t[1920 + d * 128 + q];                       // leaf value
        }
        out[p] = acc * 0.0625f;   // mean over 16 dims (exact /16)
    }
}

extern "C" void kernel_launch(void* const* d_in, const int* in_sizes, int n_in,
                              void* d_out, int out_size, void* d_ws, size_t ws_size,
                              hipStream_t stream) {
    const float* x       = (const float*)d_in[0];   // (n,16) f32
    const float* samples = (const float*)d_in[1];   // (16,255) f32
    float* out = (float*)d_out;
    const int n = in_sizes[0] / DIMS;
    float* ws = (float*)d_ws;                       // 16 KB tables

    build_luts<<<(DIMS * NODES + 255) / 256, 256, 0, stream>>>(samples, ws);

    // 1024 blocks = 4 blocks/CU (launch_bounds 256,4) -> 16 waves/CU
    int blocks = (n + 255) / 256;
    if (blocks > 1024) blocks = 1024;
    polya_eval<<<blocks, 256, 0, stream>>>(x, ws, out, n);
}

// Round 8
// 34.165 us; speedup vs baseline: 1.5110x; 1.4893x over previous
//
#include <hip/hip_runtime.h>
#include <math.h>

// PolyaTree R8: R3 descent (proven bit-exact, absmax 0.03) with ONLY levels
// 0-1 resolved from registers (3 wave-uniform splits/dim = 48 values, SGPR/
// VGPR resident -- R7's 112-value version spilled). Levels 2-6 + leaf value
// stay as 6 narrow b32 LDS gathers/point-dim (was 8 in R3).
// amdgpu_waves_per_eu(4,4) pins the compiler to the 128-VGPR config so it
// cannot choose 8-waves+spill (R7's failure: VGPR=64, WRITE_SIZE=45MB).

constexpr int DIMS  = 16;
constexpr int NODES = 255;

// ws layout (floats)
constexpr int TOP_OFF = 0;      // 16*4 : splits of nodes 0,1,2 (+pad)
constexpr int STG_OFF = 64;     // staged-to-LDS region begins here:
//   L2 : base    0 + d*4   (nodes 3..6)      64 floats
//   L3 : base   64 + d*8   (nodes 7..14)    128
//   L4 : base  192 + d*16  (nodes 15..30)   256
//   L5 : base  448 + d*32  (nodes 31..62)   512
//   L6 : base  960 + d*64  (nodes 63..126) 1024
//   VAL: base 1984 + d*128 (leaves)        2048
constexpr int LDS_F = 4032;     // 15.75 KB
constexpr int WS_F  = STG_OFF + LDS_F;

// --- exact-mirror node interval descent (validated R3/R5/R6/R7) ---
__device__ void node_lohi(const float* s, int j, float& lo, float& hi, float& acc) {
#pragma clang fp contract(off)
    unsigned key = (unsigned)(j + 1);   // 1 then path bits (0 = left)
    int level = 31 - __clz(key);
    lo = 0.0f; hi = 1.0f; acc = 0.0f;
    int i = 0;
    for (int tb = level - 1; tb >= 0; --tb) {
        float b = s[i];
        acc += logf(b);
        float len = hi - lo;
        float split = lo + b * len;     // EXACT mirror of reference (no fma)
        unsigned bit = (key >> tb) & 1u;
        if (bit == 0u) { hi = split; }
        else { lo = split; hi = split + (1.0f - b) * len; }
        i = 2 * i + 1 + (int)bit;
    }
}

__global__ void build_luts(const float* __restrict__ samples, // (16,255)
                           float* __restrict__ ws)            // WS_F floats
{
#pragma clang fp contract(off)
    int t = blockIdx.x * blockDim.x + threadIdx.x;
    if (t >= DIMS * NODES) return;
    int d = t / NODES;
    int j = t - d * NODES;
    const float* s = samples + d * NODES;

    float lo, hi, acc;
    node_lohi(s, j, lo, hi, acc);
    float b = s[j];
    float* stg = ws + STG_OFF;
    if (j < 127) {
        float split = lo + b * (hi - lo);             // exact mirror
        if (j < 3)        ws[TOP_OFF + d * 4 + j]          = split;
        else if (j < 7)   stg[         d * 4   + (j - 3)]  = split;
        else if (j < 15)  stg[  64  +  d * 8   + (j - 7)]  = split;
        else if (j < 31)  stg[ 192  +  d * 16  + (j - 15)] = split;
        else if (j < 63)  stg[ 448  +  d * 32  + (j - 31)] = split;
        else              stg[ 960  +  d * 64  + (j - 63)] = split;
    } else {
        stg[1984 + d * 128 + (j - 127)] = acc + logf(b) - logf(hi - lo);
    }
}

__global__ __launch_bounds__(256)
__attribute__((amdgpu_waves_per_eu(4, 4)))
void polya_eval(
    const float* __restrict__ x,     // (n,16)
    const float* __restrict__ tbl,   // ws
    float* __restrict__ out,
    int n)
{
    __shared__ float s_t[LDS_F];     // lvl2..6 + values, 15.75 KB
    for (int i = threadIdx.x; i < LDS_F; i += 256) s_t[i] = tbl[STG_OFF + i];
    __syncthreads();

    // levels 0-1: 3 wave-uniform splits per dim, loaded once (s_load, hoisted)
    float S0[DIMS], S1[DIMS], S2[DIMS];   // 48 values
#pragma unroll
    for (int d = 0; d < DIMS; ++d) {
        const float* t = tbl + TOP_OFF + d * 4;
        S0[d] = t[0]; S1[d] = t[1]; S2[d] = t[2];
    }

    const int stride = gridDim.x * 256;
    for (int p = blockIdx.x * 256 + threadIdx.x; p < n; p += stride) {
        const float4* xr = reinterpret_cast<const float4*>(x + (size_t)p * DIMS);
        float4 a = xr[0], b4 = xr[1], c4 = xr[2], e4 = xr[3];
        float xs[DIMS] = {a.x, a.y, a.z, a.w,  b4.x, b4.y, b4.z, b4.w,
                          c4.x, c4.y, c4.z, c4.w,  e4.x, e4.y, e4.z, e4.w};
        float acc = 0.0f;
#pragma unroll
        for (int d = 0; d < DIMS; ++d) {
            const float xv = xs[d];
            // levels 0-1: pure VALU from registers
            const int b0 = (int)(xv > S0[d]);
            const float m1 = b0 ? S2[d] : S1[d];
            int q = (b0 << 1) | (int)(xv > m1);                   // 2 bits
            // levels 2-6 + value: 6 narrow b32 LDS gathers
            q = (q << 1) | (int)(xv > s_t[        (d << 2) + q]); // lvl2
            q = (q << 1) | (int)(xv > s_t[  64 +  (d << 3) + q]); // lvl3
            q = (q << 1) | (int)(xv > s_t[ 192 +  (d << 4) + q]); // lvl4
            q = (q << 1) | (int)(xv > s_t[ 448 +  (d << 5) + q]); // lvl5
            q = (q << 1) | (int)(xv > s_t[ 960 +  (d << 6) + q]); // lvl6
            acc += s_t[1984 + (d << 7) + q];                      // leaf value
        }
        out[p] = acc * 0.0625f;   // mean over 16 dims (exact /16)
    }
}

extern "C" void kernel_launch(void* const* d_in, const int* in_sizes, int n_in,
                              void* d_out, int out_size, void* d_ws, size_t ws_size,
                              hipStream_t stream) {
    const float* x       = (const float*)d_in[0];   // (n,16) f32
    const float* samples = (const float*)d_in[1];   // (16,255) f32
    float* out = (float*)d_out;
    const int n = in_sizes[0] / DIMS;
    float* ws = (float*)d_ws;                       // 16 KB tables

    build_luts<<<(DIMS * NODES + 255) / 256, 256, 0, stream>>>(samples, ws);

    int blocks = (n + 255) / 256;                   // R3-proven config
    if (blocks > 2048) blocks = 2048;
    polya_eval<<<blocks, 256, 0, stream>>>(x, ws, out, n);
}